// Round 6
// baseline (31.044 us; speedup 1.0000x reference)
//
#include <hip/hip_runtime.h>

// Problem constants (from reference): B=32, S=256, C=50, L=20, F=30, W=3
constexpr int Bc = 32;
constexpr int Sc = 256;
constexpr int Cc = 50;
constexpr int Lc = 20;
constexpr int Fc = 30;
constexpr int Wc = 3;
constexpr int OUT_CH   = Cc * Fc;       // 1500
constexpr int CONV_LEN = Lc - Wc + 1;   // 18 -> 9 packed pairs
constexpr int XSZ      = Cc * Lc;       // 1000 floats per (b,s)
constexpr int BLOCK    = 256;
constexpr int CH_PER_T = 6;             // 6t..6t+5 never crosses a group boundary
constexpr int NP       = 8;             // positions per block (weights amortized 8x)
constexpr int ACT      = OUT_CH / CH_PER_T;   // 250 active lanes (== XSZ/4 stagers)

typedef float f32x2 __attribute__((ext_vector_type(2)));
typedef float f32x4 __attribute__((ext_vector_type(4)));

// Packed fp32: one VOP3P inst = 2 lanes' worth of fp32 math (gfx90a+/gfx950).
static __device__ __forceinline__ f32x2 pk_fma(f32x2 a, f32x2 b, f32x2 c) {
    f32x2 d;
    asm("v_pk_fma_f32 %0, %1, %2, %3" : "=v"(d) : "v"(a), "v"(b), "v"(c));
    return d;
}
static __device__ __forceinline__ f32x2 pk_mul(f32x2 a, f32x2 b) {
    f32x2 d;
    asm("v_pk_mul_f32 %0, %1, %2" : "=v"(d) : "v"(a), "v"(b));
    return d;
}

// Barrier with lgkmcnt(0) only: own ds ops drained (write visibility + WAR);
// global prefetch loads stay in flight across the barrier (proven correct R4).
static __device__ __forceinline__ void block_sync() {
    asm volatile("s_waitcnt lgkmcnt(0)" ::: "memory");
    __builtin_amdgcn_s_barrier();
    asm volatile("" ::: "memory");
}

__global__ __launch_bounds__(BLOCK, 4)
void charcnn_kernel(const float* __restrict__ x,      // [B*S, C, L]
                    const float* __restrict__ weight, // [C*F, 1, W]
                    const float* __restrict__ bias,   // [C*F]
                    float* __restrict__ out)          // [B*S, C*F]
{
    __shared__ float xs[2][XSZ];        // double-buffered 4 KB slabs

    const int t    = threadIdx.x;
    const int pos0 = blockIdx.x * NP;
    const bool on  = (t < ACT);         // same 250 lanes stage and compute

    // ---- weights/bias once per thread (register-resident across NP positions)
    float w[CH_PER_T * Wc];             // 18 contiguous floats -> 9x float2
    float bb[CH_PER_T];                 // 6 contiguous floats  -> 3x float2
    if (on) {
        const float2* wp = (const float2*)(weight + t * (CH_PER_T * Wc));
        #pragma unroll
        for (int i = 0; i < (CH_PER_T * Wc) / 2; ++i) {
            const float2 q = wp[i];
            w[2*i] = q.x; w[2*i+1] = q.y;
        }
        const float2* bp = (const float2*)(bias + t * CH_PER_T);
        #pragma unroll
        for (int i = 0; i < CH_PER_T / 2; ++i) {
            const float2 q = bp[i];
            bb[2*i] = q.x; bb[2*i+1] = q.y;
        }
    }

    const int c = t / 5;                // group shared by this thread's 6 channels

    // ---- prologue: slab0 -> xs[0]; slab1 held in preA (ds_write at end of p=0)
    float4 preA, preB;
    if (on) {
        float4 s0 = ((const float4*)(x + (size_t)(pos0 + 0) * XSZ))[t];
        preA      = ((const float4*)(x + (size_t)(pos0 + 1) * XSZ))[t];
        ((float4*)xs[0])[t] = s0;
    }
    block_sync();

    #pragma unroll
    for (int p = 0; p < NP; ++p) {
        const int buf = p & 1;

        // Load for position p+2 issues now; ds_write happens at end of p+1.
        if (on && (p + 2 < NP))
            preB = ((const float4*)(x + (size_t)(pos0 + p + 2) * XSZ))[t];

        if (on) {
            // Row (80 B) -> 5x ds_read_b128 -> 10 even pairs (free splits).
            f32x2 ev[10];
            {
                const f32x4* rowv = (const f32x4*)(xs[buf] + c * Lc);
                #pragma unroll
                for (int i = 0; i < Lc / 4; ++i) {
                    const f32x4 q = rowv[i];
                    ev[2*i]   = __builtin_shufflevector(q, q, 0, 1);
                    ev[2*i+1] = __builtin_shufflevector(q, q, 2, 3);
                }
            }
            // 9 odd pairs (v[2i+1], v[2i+2]); built once, used by all 6 filters.
            f32x2 od[CONV_LEN / 2];
            #pragma unroll
            for (int i = 0; i < CONV_LEN / 2; ++i) {
                f32x2 o; o[0] = ev[i][1]; o[1] = ev[i + 1][0];
                od[i] = o;
            }

            float res[CH_PER_T];
            #pragma unroll
            for (int j = 0; j < CH_PER_T; ++j) {
                const float w0 = w[3*j + 0];
                const float w1 = w[3*j + 1];
                const float w2 = w[3*j + 2];
                f32x2 w00; w00[0] = w0; w00[1] = w0;
                f32x2 w11; w11[0] = w1; w11[1] = w1;
                f32x2 w22; w22[0] = w2; w22[1] = w2;

                // cv[2i],cv[2i+1] in one pk chain: 27 VOP3P vs 54 scalar ops.
                float m;
                #pragma unroll
                for (int i = 0; i < CONV_LEN / 2; ++i) {
                    const f32x2 p2 = pk_fma(ev[i], w00,
                                     pk_fma(od[i], w11,
                                     pk_mul(ev[i + 1], w22)));
                    m = (i == 0) ? fmaxf(p2[0], p2[1])
                                 : fmaxf(fmaxf(m, p2[0]), p2[1]);  // v_max3
                }
                res[j] = m + bb[j];     // bias invariant over window: hoisted past max
            }

            // Stage slab p+1 into the other buffer (readers separated by barrier).
            if (p + 1 < NP)
                ((float4*)xs[buf ^ 1])[t] = preA;

            // 6 floats at out + (pos0+p)*1500 + 6t: contiguous across lanes.
            float* op = out + (size_t)(pos0 + p) * OUT_CH + t * CH_PER_T;
            #pragma unroll
            for (int i = 0; i < CH_PER_T / 2; ++i)
                ((float2*)op)[i] = make_float2(res[2*i], res[2*i+1]);

            preA = preB;                // slab p+2 becomes next to stage
        }

        if (p + 1 < NP) block_sync();   // lgkmcnt-only: prefetch survives barrier
    }
}

extern "C" void kernel_launch(void* const* d_in, const int* in_sizes, int n_in,
                              void* d_out, int out_size, void* d_ws, size_t ws_size,
                              hipStream_t stream) {
    const float* x      = (const float*)d_in[0];  // [B,S,C,L] fp32
    const float* weight = (const float*)d_in[1];  // [C*F,1,W] fp32
    const float* bias   = (const float*)d_in[2];  // [C*F] fp32
    float* out          = (float*)d_out;          // [B,S,C*F] fp32

    const int nBlocks = (Bc * Sc) / NP;           // 1024 blocks (16 waves/CU resident)
    charcnn_kernel<<<nBlocks, BLOCK, 0, stream>>>(x, weight, bias, out);
}

// Round 7
// 29.077 us; speedup vs baseline: 1.0677x; 1.0677x over previous
//
#include <hip/hip_runtime.h>

// Problem constants (from reference): B=32, S=256, C=50, L=20, F=30, W=3
constexpr int Bc = 32;
constexpr int Sc = 256;
constexpr int Cc = 50;
constexpr int Lc = 20;
constexpr int Fc = 30;
constexpr int Wc = 3;
constexpr int OUT_CH   = Cc * Fc;       // 1500
constexpr int CONV_LEN = Lc - Wc + 1;   // 18
constexpr int XSZ      = Cc * Lc;       // 1000 floats per (b,s)
constexpr int BLOCK    = 256;
constexpr int CH_PER_T = 6;             // 6t..6t+5 never crosses a group boundary
constexpr int NP       = 4;             // positions per block
constexpr int ACT      = OUT_CH / CH_PER_T;   // 250 active compute lanes
constexpr int OUTV     = OUT_CH / 4;    // 375 float4 stores per position

// Barrier with lgkmcnt(0) only: retires this wave's own ds ops (RAW visibility
// + WAR on shared buffers); global prefetch loads stay in flight across it.
static __device__ __forceinline__ void block_sync() {
    asm volatile("s_waitcnt lgkmcnt(0)" ::: "memory");
    __builtin_amdgcn_s_barrier();
    asm volatile("" ::: "memory");
}

__global__ __launch_bounds__(BLOCK, 4)
void charcnn_kernel(const float* __restrict__ x,      // [B*S, C, L]
                    const float* __restrict__ weight, // [C*F, 1, W]
                    const float* __restrict__ bias,   // [C*F]
                    float* __restrict__ out)          // [B*S, C*F]
{
    __shared__ float xs[2][XSZ];        // double-buffered 4 KB input slabs
    __shared__ float outs[OUT_CH];      // 6 KB store-coalescing stage

    const int t    = threadIdx.x;
    const int pos0 = blockIdx.x * NP;
    const bool on  = (t < ACT);         // 250 lanes stage inputs and compute

    // ---- weights/bias once per thread (register-resident across NP positions)
    float w[CH_PER_T * Wc];             // 18 contiguous floats -> 9x float2
    float bb[CH_PER_T];                 // 6 contiguous floats  -> 3x float2
    if (on) {
        const float2* wp = (const float2*)(weight + t * (CH_PER_T * Wc));
        #pragma unroll
        for (int i = 0; i < (CH_PER_T * Wc) / 2; ++i) {
            const float2 q = wp[i];
            w[2*i] = q.x; w[2*i+1] = q.y;
        }
        const float2* bp = (const float2*)(bias + t * CH_PER_T);
        #pragma unroll
        for (int i = 0; i < CH_PER_T / 2; ++i) {
            const float2 q = bp[i];
            bb[2*i] = q.x; bb[2*i+1] = q.y;
        }
    }

    const int c = t / 5;                // group shared by this thread's 6 channels

    // ---- prologue: slab0 -> xs[0]; slab1 held in preA (ds_write at end of p=0)
    float4 preA, preB;
    if (on) {
        float4 s0 = ((const float4*)(x + (size_t)(pos0 + 0) * XSZ))[t];
        preA      = ((const float4*)(x + (size_t)(pos0 + 1) * XSZ))[t];
        ((float4*)xs[0])[t] = s0;
    }
    block_sync();

    #pragma unroll
    for (int p = 0; p < NP; ++p) {
        const int buf = p & 1;

        // Load for position p+2 issues now; its ds_write lands at end of p+1.
        if (on && (p + 2 < NP))
            preB = ((const float4*)(x + (size_t)(pos0 + p + 2) * XSZ))[t];

        if (on) {
            // Row: 80 B, 16B-aligned -> 5x ds_read_b128.
            float v[Lc];
            const float4* rowv = (const float4*)(xs[buf] + c * Lc);
            #pragma unroll
            for (int i = 0; i < Lc / 4; ++i) {
                const float4 q = rowv[i];
                v[4*i+0] = q.x; v[4*i+1] = q.y; v[4*i+2] = q.z; v[4*i+3] = q.w;
            }

            float res[CH_PER_T];
            #pragma unroll
            for (int j = 0; j < CH_PER_T; ++j) {
                const float w0 = w[3*j + 0];
                const float w1 = w[3*j + 1];
                const float w2 = w[3*j + 2];

                float cv[CONV_LEN];
                #pragma unroll
                for (int q = 0; q < CONV_LEN; ++q)
                    cv[q] = fmaf(v[q], w0, fmaf(v[q+1], w1, v[q+2] * w2));

                float m = fmaxf(fmaxf(cv[0], cv[1]), cv[2]);
                #pragma unroll
                for (int q = 3; q + 1 < CONV_LEN; q += 2)
                    m = fmaxf(fmaxf(m, cv[q]), cv[q+1]);   // v_max3 fusion
                m = fmaxf(m, cv[CONV_LEN - 1]);

                res[j] = m + bb[j];     // bias invariant over window: hoisted past max
            }

            // Results -> LDS stage (3x ds_write_b64 at stride 24B: 2-way banks, free).
            float2* os = (float2*)(outs + t * CH_PER_T);
            #pragma unroll
            for (int i = 0; i < CH_PER_T / 2; ++i)
                os[i] = make_float2(res[2*i], res[2*i+1]);

            // Stage slab p+1 into the other buffer (compiler waits only its vmcnt).
            if (p + 1 < NP)
                ((float4*)xs[buf ^ 1])[t] = preA;
            preA = preB;
        }

        block_sync();                   // outs complete; xs[buf^1] staged

        // Coalesced store: lane-contiguous float4 runs (1 KB per wave-store).
        {
            const float4* ov = (const float4*)outs;
            float4*       op = (float4*)(out + (size_t)(pos0 + p) * OUT_CH);
            op[t] = ov[t];                                  // floats 0..1023
            if (t < OUTV - BLOCK) op[t + BLOCK] = ov[t + BLOCK];  // 1024..1499
        }

        // Loop-top barrier of next iteration (lgkmcnt drains the outs ds_reads)
        // protects outs against next position's writes (WAR).
        if (p + 1 < NP) block_sync();
    }
}

extern "C" void kernel_launch(void* const* d_in, const int* in_sizes, int n_in,
                              void* d_out, int out_size, void* d_ws, size_t ws_size,
                              hipStream_t stream) {
    const float* x      = (const float*)d_in[0];  // [B,S,C,L] fp32
    const float* weight = (const float*)d_in[1];  // [C*F,1,W] fp32
    const float* bias   = (const float*)d_in[2];  // [C*F] fp32
    float* out          = (float*)d_out;          // [B,S,C*F] fp32

    const int nBlocks = (Bc * Sc) / NP;           // 2048 blocks (8 blocks/CU)
    charcnn_kernel<<<nBlocks, BLOCK, 0, stream>>>(x, weight, bias, out);
}